// Round 4
// baseline (411.166 us; speedup 1.0000x reference)
//
#include <hip/hip_runtime.h>
#include <hip/hip_bf16.h>
#include <hip/hip_fp16.h>

// Problem constants
#define N_NODES 10000
#define N_EDGES 128000
constexpr int C = 128;
constexpr int A = 10;

constexpr float INV_SQRT_C  = 0.08838834764831845f;   // 1/sqrt(128)
constexpr float INV_SQRT_R  = 0.35355339059327373f;   // 1/sqrt(8)
constexpr float INV_SQRT_64 = 0.125f;                 // 1/sqrt(64)
constexpr float INV_SQRT_CA = 0.027950849718747374f;  // 1/sqrt(1280)
constexpr float INV_SQRT_2C = 0.0625f;                // 1/sqrt(256)
constexpr float INV_SQRT_3  = 0.57735026918962576f;

typedef short short8 __attribute__((ext_vector_type(8)));
typedef _Float16 f16x8 __attribute__((ext_vector_type(8)));
typedef _Float16 f16x2 __attribute__((ext_vector_type(2)));
typedef float f32x4 __attribute__((ext_vector_type(4)));

__device__ __forceinline__ float silu_f(float x) { return x / (1.0f + __expf(-x)); }

__device__ __forceinline__ void atomic_add_f32(float* p, float v) {
  __hip_atomic_fetch_add(p, v, __ATOMIC_RELAXED, __HIP_MEMORY_SCOPE_AGENT);
}

__device__ __forceinline__ unsigned short f2h(float f) {
  return __builtin_bit_cast(unsigned short, (_Float16)f);  // RNE
}

__device__ __forceinline__ float h2f(unsigned short us) {
  return (float)__builtin_bit_cast(_Float16, us);
}

__device__ __forceinline__ unsigned int pk2h(float a, float b) {
  auto h = __builtin_amdgcn_cvt_pkrtz(a, b);  // __fp16 ext_vector(2)
  return __builtin_bit_cast(unsigned int, h);
}

__device__ __forceinline__ unsigned int pkmul_h2(unsigned int x, unsigned int y) {
  const f16x2 a = __builtin_bit_cast(f16x2, x), b = __builtin_bit_cast(f16x2, y);
  return __builtin_bit_cast(unsigned int, a * b);  // v_pk_mul_f16
}

// ---------------------------------------------------------------------------
// K1: split-H outputs (gather dedup in k_mlp_msg):
//   H0[n*128 + v]        = h0[n,v]                (fp16)
//   H1[n*384 + 3v + k]   = h1[n,v,k], k=0..2      (fp16, u-major)
// ---------------------------------------------------------------------------
__global__ __launch_bounds__(256) void k_node_up(
    const float* __restrict__ nf, const float* __restrict__ Wu0,
    const float* __restrict__ Wu1, __half* __restrict__ H0,
    __half* __restrict__ H1) {
  __shared__ __align__(16) float xs[8][C][4];
  const int t = threadIdx.x;
  const int n0 = blockIdx.x * 8;
  for (int idx = t; idx < 8 * 512; idx += 256) {
    const int nn = idx >> 9, q = idx & 511;
    const float val = nf[(size_t)(n0 + nn) * 512 + q];
    if (q < C) xs[nn][q][0] = val;
    else { const int r = q - C; xs[nn][r / 3][1 + r % 3] = val; }
  }
  __syncthreads();
  const int g = t >> 7, v = t & 127;
  float acc[4][4] = {};
  for (int u = 0; u < C; ++u) {
    const float w0 = Wu0[u * C + v];
    const float w1 = Wu1[u * C + v];
#pragma unroll
    for (int nn = 0; nn < 4; ++nn) {
      const float4 xv = *(const float4*)&xs[g * 4 + nn][u][0];
      acc[nn][0] = fmaf(xv.x, w0, acc[nn][0]);
      acc[nn][1] = fmaf(xv.y, w1, acc[nn][1]);
      acc[nn][2] = fmaf(xv.z, w1, acc[nn][2]);
      acc[nn][3] = fmaf(xv.w, w1, acc[nn][3]);
    }
  }
#pragma unroll
  for (int nn = 0; nn < 4; ++nn) {
    const int n = n0 + g * 4 + nn;
    H0[(size_t)n * 128 + v] =
        __builtin_bit_cast(__half, f2h(acc[nn][0] * INV_SQRT_C));
    __half* q = &H1[(size_t)n * 384 + 3 * v];
    q[0] = __builtin_bit_cast(__half, f2h(acc[nn][1] * INV_SQRT_C));
    q[1] = __builtin_bit_cast(__half, f2h(acc[nn][2] * INV_SQRT_C));
    q[2] = __builtin_bit_cast(__half, f2h(acc[nn][3] * INV_SQRT_C));
  }
}

// ---------------------------------------------------------------------------
// cvtw helper: weight (K x N fp32, row-major) -> f16 A-operand swizzle of W^T.
// ---------------------------------------------------------------------------
__device__ __forceinline__ void cvtw(const float* __restrict__ src,
                                     unsigned short* __restrict__ dst,
                                     int idx, int lgN, int KT) {
  const int k = idx >> lgN;
  const int n = idx & ((1 << lgN) - 1);
  dst[((n * KT + (k >> 5)) << 5) + (k & 31)] = f2h(src[idx]);
}

// ---------------------------------------------------------------------------
// k_prep (merged): skip-weight cvt (f16, k'=a*128+u permuted) + 3x cvt_w +
// edge histogram. All-independent elementwise work, one launch.
// ---------------------------------------------------------------------------
__global__ __launch_bounds__(256) void k_prep(
    const float* __restrict__ W0, const float* __restrict__ W1,
    unsigned short* __restrict__ B0, unsigned short* __restrict__ B1,
    const float* __restrict__ R1, unsigned short* __restrict__ R1a,
    const float* __restrict__ R2, unsigned short* __restrict__ R2a,
    const float* __restrict__ R3, unsigned short* __restrict__ R3a,
    const int* __restrict__ eidx, int* __restrict__ counts) {
  const int b = blockIdx.x, t = threadIdx.x;
  if (b < 640) {
    // skip GEMM B operand: k = u*10+a -> permuted k' = a*128+u (so the
    // A-repack in k_skip_mfma has constant a / contiguous u per 8-chunk).
    const int idx = b * 256 + t;
    const int k = idx >> 7, col = idx & 127;
    const int u = k / 10, a = k - u * 10;
    const int kp = a * 128 + u;
    const int dst = ((kp >> 5) * 128 + col) * 32 + (kp & 31);
    B0[dst] = f2h(W0[idx]);
    B1[dst] = f2h(W1[idx]);
  } else if (b < 656) {
    cvtw(R1, R1a, (b - 640) * 256 + t, 6, 2);
  } else if (b < 672) {
    cvtw(R2, R2a, (b - 656) * 256 + t, 6, 2);
  } else if (b < 800) {
    cvtw(R3, R3a, (b - 672) * 256 + t, 9, 2);
  } else {
    const int e = (b - 800) * 256 + t;
    if (e < N_EDGES) atomicAdd(&counts[eidx[N_EDGES + e]], 1);
  }
}

// ---------------------------------------------------------------------------
// K2 (MFMA): sc as two f16 GEMMs with k' = a*128+u contraction order.
// attr row register-cached; repack per K-step = 1 ds_read_b128 +
// 4 v_pk_mul_f16 + 1 ds_write_b128. xs padded [64][136].
// ---------------------------------------------------------------------------
__global__ __launch_bounds__(256) void k_skip_mfma(
    const float* __restrict__ nf, const float* __restrict__ attrs,
    const unsigned short* __restrict__ B0, const unsigned short* __restrict__ B1,
    float* __restrict__ out_sc) {
  __shared__ __align__(16) unsigned short xs[64][136];     // 17 KB f16 (+pad)
  __shared__ float at[64][10];                             // 2.5 KB
  __shared__ __align__(16) unsigned short zs[2][64][40];   // 10 KB

  const int t = threadIdx.x;
  const int wave = t >> 6, lane = t & 63;
  const bool isG0 = blockIdx.x < 157;
  const int r0 = isG0 ? blockIdx.x * 64 : (blockIdx.x - 157) * 64;
  const int rcount = isG0 ? 10000 : 30000;
  const unsigned short* __restrict__ Bsw = isG0 ? B0 : B1;

  for (int idx = t; idx < 64 * 128; idx += 256) {
    const int i = idx >> 7, u = idx & 127;
    const int r = r0 + i;
    float v = 0.f;
    if (r < rcount) {
      if (isG0) v = nf[(size_t)r * 512 + u];
      else {
        const int n = r / 3, kc = r - n * 3;
        v = nf[(size_t)n * 512 + 128 + u * 3 + kc];
      }
    }
    xs[i][u] = f2h(v);
  }
  for (int idx = t; idx < 640; idx += 256) {
    const int i = idx / 10, a = idx - (idx / 10) * 10;
    const int r = r0 + i;
    float v = 0.f;
    if (r < rcount) v = attrs[(size_t)(isG0 ? r : r / 3) * 10 + a];
    at[i][a] = v;
  }
  __syncthreads();

  const int m = lane & 15, q = lane >> 4;
  const int colB = wave * 32;
  const int rr = t >> 2;
  const int off = (t & 3) * 8;

  // attr row -> 10 half2-broadcast registers (compile-time indexed below)
  unsigned int atr2[10];
#pragma unroll
  for (int a = 0; a < 10; ++a) {
    const unsigned int h = f2h(at[rr][a]);
    atr2[a] = h | (h << 16);
  }

  f32x4 acc[4][2];
#pragma unroll
  for (int rt = 0; rt < 4; ++rt)
#pragma unroll
    for (int ct = 0; ct < 2; ++ct) acc[rt][ct] = (f32x4){0.f, 0.f, 0.f, 0.f};

#pragma unroll
  for (int a = 0; a < 10; ++a) {
    const unsigned int av2 = atr2[a];
#pragma unroll
    for (int kk = 0; kk < 4; ++kk) {
      const int kt = a * 4 + kk;
      const int buf = kt & 1;
      {
        // k' = a*128 + (kk*32 + off + j): constant a, contiguous u
        const uint4 xv = *(const uint4*)&xs[rr][kk * 32 + off];
        uint4 z;
        z.x = pkmul_h2(xv.x, av2);
        z.y = pkmul_h2(xv.y, av2);
        z.z = pkmul_h2(xv.z, av2);
        z.w = pkmul_h2(xv.w, av2);
        *(uint4*)&zs[buf][rr][off] = z;
      }
      __syncthreads();

      f16x8 bfrag[2];
#pragma unroll
      for (int ct = 0; ct < 2; ++ct) {
        const unsigned short* bp =
            &Bsw[(size_t)(kt * 128 + colB + ct * 16 + m) * 32 + q * 8];
        bfrag[ct] = *(const f16x8*)bp;
      }
#pragma unroll
      for (int rt = 0; rt < 4; ++rt) {
        const f16x8 afrag = *(const f16x8*)&zs[buf][rt * 16 + m][q * 8];
#pragma unroll
        for (int ct = 0; ct < 2; ++ct)
          acc[rt][ct] = __builtin_amdgcn_mfma_f32_16x16x32_f16(
              afrag, bfrag[ct], acc[rt][ct], 0, 0, 0);
      }
      // no trailing barrier: next iteration writes the other zs buffer
    }
  }

#pragma unroll
  for (int rt = 0; rt < 4; ++rt) {
#pragma unroll
    for (int reg = 0; reg < 4; ++reg) {
      const int rloc = rt * 16 + q * 4 + reg;
      const int r = r0 + rloc;
      if (r < rcount) {
#pragma unroll
        for (int ct = 0; ct < 2; ++ct) {
          const int v = colB + ct * 16 + m;
          const float val = acc[rt][ct][reg] * INV_SQRT_CA;
          if (isG0) {
            out_sc[(size_t)r * 512 + v] = val;
          } else {
            const int n = r / 3, kc = r - (r / 3) * 3;
            out_sc[(size_t)n * 512 + 128 + v * 3 + kc] = val;
          }
        }
      }
    }
  }
}

// ---------------------------------------------------------------------------
// Sort-by-receiver: scan -> scatter (histogram lives in k_prep)
// ---------------------------------------------------------------------------
__global__ __launch_bounds__(1024) void k_scan(const int* __restrict__ counts,
                                               int* __restrict__ offsets,
                                               int* __restrict__ cursor) {
  __shared__ int part[1024];
  const int t = threadIdx.x;
  int local[10];
  int s = 0;
#pragma unroll
  for (int i = 0; i < 10; ++i) {
    const int idx = t * 10 + i;
    const int c = (idx < N_NODES) ? counts[idx] : 0;
    local[i] = s;
    s += c;
  }
  part[t] = s;
  __syncthreads();
  for (int off = 1; off < 1024; off <<= 1) {
    const int add = (t >= off) ? part[t - off] : 0;
    __syncthreads();
    part[t] += add;
    __syncthreads();
  }
  const int pre = (t > 0) ? part[t - 1] : 0;
#pragma unroll
  for (int i = 0; i < 10; ++i) {
    const int idx = t * 10 + i;
    if (idx < N_NODES) {
      const int o = pre + local[i];
      offsets[idx] = o;
      cursor[idx] = o;
    }
  }
  if (t == 1023) offsets[N_NODES] = part[1023];
}

__global__ __launch_bounds__(256) void k_scatter(
    const int* __restrict__ eidx, const float* __restrict__ ea_g,
    const float* __restrict__ ef_g,
    int* __restrict__ cursor,
    int* __restrict__ snd_s, int* __restrict__ rcv_s,
    float* __restrict__ ea_s, float* __restrict__ ef_s) {
  const int e = blockIdx.x * 256 + threadIdx.x;
  if (e < N_EDGES) {
    const int r = eidx[N_EDGES + e];
    const int pos = atomicAdd(&cursor[r], 1);
    snd_s[pos] = eidx[e];
    rcv_s[pos] = r;
    ((float4*)ea_s)[pos] = ((const float4*)ea_g)[e];
    ((float4*)ef_s)[pos * 2]     = ((const float4*)ef_g)[e * 2];
    ((float4*)ef_s)[pos * 2 + 1] = ((const float4*)ef_g)[e * 2 + 1];
  }
}

// ---------------------------------------------------------------------------
// K3 (fused): edge MLP (MFMA) + message formation + segmented reduction.
// Pair-tile L4: wave w computes channel tiles {base..base+3} U {base+8..+11};
// each lane holds channel pairs -> message loop reads ONE ds_read_b32/edge.
//
// v3: barrier-free chunk loop + offsets prefetch at segment start.
// v5 (this round):
//  * REVERTED the v4 depth-16 prefetch (it spilled: FETCH+27MB/WRITE+16MB
//    scratch signature at pinned VGPR=64). Back to proven depth-8 hA/hB.
//  * Split-H gather dedup: half0 loads 2B from H0, half1 loads 2x4B window
//    from u-major H1 + shift-extract. Gather bytes/edge 2KB -> ~1.15KB.
//  * rc/sn message-loop reads batched as int4 (1 ds_read_b128 vs 4 b32);
//    sn padded to 144 (node 0) so the tail refill read is branch-free.
// ---------------------------------------------------------------------------
__global__ __launch_bounds__(256, 4) void k_mlp_msg(
    const float* __restrict__ ef_s, const float* __restrict__ ea_s,
    const int* __restrict__ snd_s, const int* __restrict__ rcv_s,
    const int* __restrict__ offsets,
    const float* __restrict__ R0, const unsigned short* __restrict__ R1a,
    const unsigned short* __restrict__ R2a, const unsigned short* __restrict__ R3a,
    const float* __restrict__ Wd, const unsigned short* __restrict__ H0,
    const unsigned int* __restrict__ H1,
    float* __restrict__ M, float* __restrict__ density) {
  __shared__ __align__(16) unsigned short actA[128][72];  // 18 KB (live whole kernel)
  __shared__ __align__(16) unsigned char uni[18432];      // 18 KB union: efs|actB|wls2
  __shared__ __align__(16) float ys[128][4];              // 2 KB
  __shared__ __align__(16) int sn[144];                   // 576 B (refill-padded)
  __shared__ __align__(16) int rc[128];                   // 512 B
  // lifetimes: efs: stage..L1 | actB: L2..L3 | wls2: L4 chunks (all barrier-separated)
  float (*efs)[9] = (float (*)[9]) & uni[0];                       // [128][9]
  unsigned short (*actB)[72] = (unsigned short (*)[72]) & uni[0];  // [128][72]
  __half (*wls2)[536] = (__half (*)[536]) & uni[0];                // [16][536]

  const int t = threadIdx.x;
  const int wave = t >> 6, lane = t & 63, m = lane & 15, q = lane >> 4;
  const int e0 = blockIdx.x * 128;

  // stage sorted edge feats: 256 threads x float4
  {
    const float4 v = *(const float4*)&ef_s[(size_t)e0 * 8 + t * 4];
    const int e = t >> 1, c0 = (t & 1) * 4;
    efs[e][c0] = v.x; efs[e][c0 + 1] = v.y;
    efs[e][c0 + 2] = v.z; efs[e][c0 + 3] = v.w;
  }
  if (t < 128) {
    *(float4*)&ys[t][0] = ((const float4*)ea_s)[e0 + t];
    sn[t] = snd_s[e0 + t];
    rc[t] = rcv_s[e0 + t];
  } else if (t < 144) {
    sn[t] = 0;  // pad: tail refill reads sn[128..143]; node 0 is always valid
  }
  __syncthreads();

  const int u = t & 127, half = t >> 7;
  const int h1base = (3 * u) >> 1;        // uint index within H1 row (192/row)
  const unsigned int shft = (u & 1) << 4; // window alignment shift

  // per-half gather: half0 -> 2B from H0; half1 -> 8B window from H1
  auto ld_h = [&](int s) -> uint2 {
    uint2 r;
    if (half == 0) {
      r.x = H0[(size_t)s * 128 + u];
      r.y = 0;
    } else {
      const unsigned int* p = &H1[(size_t)s * 192 + h1base];
      r.x = p[0];
      r.y = p[1];
    }
    return r;
  };
  // decode to the proc-layout float4: (h0, h1x, h1y, h1z)
  auto mk_h4 = [&](uint2 hp) -> float4 {
    if (half == 0) {
      return make_float4(h2f((unsigned short)hp.x), 0.f, 0.f, 0.f);
    } else {
      unsigned long long v = ((unsigned long long)hp.y << 32) | hp.x;
      v >>= shft;
      return make_float4(0.f, h2f((unsigned short)v),
                         h2f((unsigned short)(v >> 16)),
                         h2f((unsigned short)(v >> 32)));
    }
  };

  // depth-8 H prefetch: two 4-edge groups (issued early; consumed in msg loop)
  uint2 hA[4], hB[4];
#pragma unroll
  for (int j = 0; j < 4; ++j) hA[j] = ld_h(sn[j]);
#pragma unroll
  for (int j = 0; j < 4; ++j) hB[j] = ld_h(sn[4 + j]);

  // density (one thread per edge)
  if (t < 128) {
    float s = 0.f;
#pragma unroll
    for (int i = 0; i < 8; ++i) s = fmaf(efs[t][i], Wd[i], s);
    s *= INV_SQRT_R;
    atomic_add_f32(&density[rc[t]], tanhf(s * s));
  }

  // L1: 8 -> 64 (VALU), silu, f16 into actA.
  {
    const int e = t & 127, j0 = (t >> 7) * 32;
    float a[32] = {};
#pragma unroll
    for (int i = 0; i < 8; ++i) {
      const float v = efs[e][i];
#pragma unroll
      for (int jj = 0; jj < 32; ++jj)
        a[jj] = fmaf(v, R0[i * 64 + j0 + jj], a[jj]);
    }
#pragma unroll
    for (int g = 0; g < 8; ++g) {
      uint2 pk;
      pk.x = pk2h(silu_f(a[4 * g] * INV_SQRT_R), silu_f(a[4 * g + 1] * INV_SQRT_R));
      pk.y = pk2h(silu_f(a[4 * g + 2] * INV_SQRT_R), silu_f(a[4 * g + 3] * INV_SQRT_R));
      *(uint2*)&actA[e][j0 + g * 4] = pk;
    }
  }
  __syncthreads();

  // L2: C = R1^T . actA -> silu -> actB.  (efs dead from here; actB aliases uni)
  {
    const f16x8 af0 = *(const f16x8*)&R1a[(((wave * 16 + m) * 2 + 0) << 5) + q * 8];
    const f16x8 af1 = *(const f16x8*)&R1a[(((wave * 16 + m) * 2 + 1) << 5) + q * 8];
#pragma unroll
    for (int et = 0; et < 8; ++et) {
      const f16x8 bf0 = *(const f16x8*)&actA[et * 16 + m][q * 8];
      const f16x8 bf1 = *(const f16x8*)&actA[et * 16 + m][32 + q * 8];
      f32x4 c = {0.f, 0.f, 0.f, 0.f};
      c = __builtin_amdgcn_mfma_f32_16x16x32_f16(af0, bf0, c, 0, 0, 0);
      c = __builtin_amdgcn_mfma_f32_16x16x32_f16(af1, bf1, c, 0, 0, 0);
      uint2 pk;
      pk.x = pk2h(silu_f(c[0] * INV_SQRT_64), silu_f(c[1] * INV_SQRT_64));
      pk.y = pk2h(silu_f(c[2] * INV_SQRT_64), silu_f(c[3] * INV_SQRT_64));
      *(uint2*)&actB[et * 16 + m][wave * 16 + q * 4] = pk;
    }
  }
  __syncthreads();

  // L3: C = R2^T . actB -> silu -> actA
  {
    const f16x8 af0 = *(const f16x8*)&R2a[(((wave * 16 + m) * 2 + 0) << 5) + q * 8];
    const f16x8 af1 = *(const f16x8*)&R2a[(((wave * 16 + m) * 2 + 1) << 5) + q * 8];
#pragma unroll
    for (int et = 0; et < 8; ++et) {
      const f16x8 bf0 = *(const f16x8*)&actB[et * 16 + m][q * 8];
      const f16x8 bf1 = *(const f16x8*)&actB[et * 16 + m][32 + q * 8];
      f32x4 c = {0.f, 0.f, 0.f, 0.f};
      c = __builtin_amdgcn_mfma_f32_16x16x32_f16(af0, bf0, c, 0, 0, 0);
      c = __builtin_amdgcn_mfma_f32_16x16x32_f16(af1, bf1, c, 0, 0, 0);
      uint2 pk;
      pk.x = pk2h(silu_f(c[0] * INV_SQRT_64), silu_f(c[1] * INV_SQRT_64));
      pk.y = pk2h(silu_f(c[2] * INV_SQRT_64), silu_f(c[3] * INV_SQRT_64));
      *(uint2*)&actA[et * 16 + m][wave * 16 + q * 4] = pk;
    }
  }
  __syncthreads();  // actA now final; read-only below (cross-wave) -> keep

  // L4 weights, pair-tile assignment: lower tile JL, partner JH = JL + 8.
  const int baseJ = (wave & 1) * 4 + (wave >> 1) * 16;
  f16x8 afL[4][2], afH[4][2];
#pragma unroll
  for (int i = 0; i < 4; ++i) {
#pragma unroll
    for (int kt = 0; kt < 2; ++kt) {
      const int JL = baseJ + i, JH = JL + 8;
      afL[i][kt] = *(const f16x8*)&R3a[(((JL * 16 + m) * 2 + kt) << 5) + q * 8];
      afH[i][kt] = *(const f16x8*)&R3a[(((JH * 16 + m) * 2 + kt) << 5) + q * 8];
    }
  }

  // message accumulation state
  float a0 = 0.f, a1 = 0.f, a2 = 0.f, a3 = 0.f;
  int cur = rc[0];
  int s0c = offsets[cur], s1c = offsets[cur + 1];  // segment-bound prefetch
  const int colx = (half ? 128 + u : u) * 2;

  auto flush = [&](int n, int s0, int s1) {
    float* Mp = &M[(size_t)n * 1024 + (half << 9) + (u << 2)];
    if (s0 >= e0 && s1 <= e0 + 128) {
      *(float4*)Mp = make_float4(a0, a1, a2, a3);
    } else {
      atomic_add_f32(Mp + 0, a0);
      atomic_add_f32(Mp + 1, a1);
      atomic_add_f32(Mp + 2, a2);
      atomic_add_f32(Mp + 3, a3);
    }
  };

  auto proc = [&](const uint2 hcur, unsigned int pr, const float4 yv, int n) {
    if (n != cur) {  // wave-uniform
      flush(cur, s0c, s1c);
      a0 = a1 = a2 = a3 = 0.f;
      cur = n;
      s0c = offsets[n];       // issued at segment start,
      s1c = offsets[n + 1];   // consumed at segment end -> latency hidden
    }
    const float4 h4 = mk_h4(hcur);
    const __half2 ph = __builtin_bit_cast(__half2, pr);
    const float2 pw = __half22float2(ph);
    if (half == 0) {
      a0 = fmaf(pw.x * h4.x, yv.x, a0);
      const float c1 = pw.y * h4.x;
      a1 = fmaf(c1, yv.y, a1);
      a2 = fmaf(c1, yv.z, a2);
      a3 = fmaf(c1, yv.w, a3);
    } else {
      const float dt = h4.y * yv.y + h4.z * yv.z + h4.w * yv.w;
      a0 = fmaf(pw.y * dt, INV_SQRT_3, a0);
      const float c3 = pw.x * yv.x;
      a1 = fmaf(c3, h4.y, a1);
      a2 = fmaf(c3, h4.z, a2);
      a3 = fmaf(c3, h4.w, a3);
    }
  };

  // Per 4-edge group: batch-issue the LDS reads (wls2 b32 x4, ys b128 x4,
  // rc int4, sn int4), process, refill this group's H buffer +8 ahead.
#define MSG_GROUP(G, HX)                                                    \
  {                                                                         \
    const int gb = ch * 16 + (G) * 4;                                       \
    unsigned int prv[4];                                                    \
    float4 yv4[4];                                                          \
    _Pragma("unroll") for (int j = 0; j < 4; ++j)                           \
        prv[j] = *(const unsigned int*)&wls2[(G) * 4 + j][colx];            \
    _Pragma("unroll") for (int j = 0; j < 4; ++j)                           \
        yv4[j] = *(const float4*)&ys[gb + j][0];                            \
    const int4 rc4 = *(const int4*)&rc[gb];                                 \
    proc(HX[0], prv[0], yv4[0], rc4.x);                                     \
    proc(HX[1], prv[1], yv4[1], rc4.y);                                     \
    proc(HX[2], prv[2], yv4[2], rc4.z);                                     \
    proc(HX[3], prv[3], yv4[3], rc4.w);                                     \
    const int4 sn4 = *(const int4*)&sn[gb + 8];                             \
    HX[0] = ld_h(sn4.x);                                                    \
    HX[1] = ld_h(sn4.y);                                                    \
    HX[2] = ld_h(sn4.z);                                                    \
    HX[3] = ld_h(sn4.w);                                                    \
  }

  // 8 chunks of 16 edges: L4 MFMA into wls2 (union region), then messages.
  // BARRIER-FREE: wave w writes wls2 pair-cols [w*64,(w+1)*64) and reads the
  // same range -> no cross-wave hazard; within-wave write->read ordering
  // enforced by compiler-inserted lgkmcnt.
#pragma unroll 1
  for (int ch = 0; ch < 8; ++ch) {
    {
      const f16x8 bf0 = *(const f16x8*)&actA[ch * 16 + m][q * 8];
      const f16x8 bf1 = *(const f16x8*)&actA[ch * 16 + m][32 + q * 8];
#pragma unroll
      for (int i = 0; i < 4; ++i) {
        f32x4 cL = {0.f, 0.f, 0.f, 0.f}, cH = {0.f, 0.f, 0.f, 0.f};
        cL = __builtin_amdgcn_mfma_f32_16x16x32_f16(afL[i][0], bf0, cL, 0, 0, 0);
        cL = __builtin_amdgcn_mfma_f32_16x16x32_f16(afL[i][1], bf1, cL, 0, 0, 0);
        cH = __builtin_amdgcn_mfma_f32_16x16x32_f16(afH[i][0], bf0, cH, 0, 0, 0);
        cH = __builtin_amdgcn_mfma_f32_16x16x32_f16(afH[i][1], bf1, cH, 0, 0, 0);
        uint4 pk;
        pk.x = pk2h(cL[0] * INV_SQRT_64, cH[0] * INV_SQRT_64);
        pk.y = pk2h(cL[1] * INV_SQRT_64, cH[1] * INV_SQRT_64);
        pk.z = pk2h(cL[2] * INV_SQRT_64, cH[2] * INV_SQRT_64);
        pk.w = pk2h(cL[3] * INV_SQRT_64, cH[3] * INV_SQRT_64);
        const int JL = baseJ + i;
        const int pidx0 = ((JL < 8) ? JL * 16 : (JL - 16) * 16 + 128) + q * 4;
        *(uint4*)&wls2[m][pidx0 * 2] = pk;
      }
    }
    MSG_GROUP(0, hA)
    MSG_GROUP(1, hB)
    MSG_GROUP(2, hA)
    MSG_GROUP(3, hB)
  }
#undef MSG_GROUP
  flush(cur, s0c, s1c);
}

// ---------------------------------------------------------------------------
// K5: out0 = M0 @ Wl0 /16/denom; out1[.,.,k] = M1[...,k] @ Wl1 /16/denom
// ---------------------------------------------------------------------------
__global__ __launch_bounds__(256) void k_out(
    const float* __restrict__ M, const float* __restrict__ density,
    const float* __restrict__ Wl0, const float* __restrict__ Wl1,
    float* __restrict__ out) {
  __shared__ __align__(16) float Ms[8][256][4];  // 32 KB
  __shared__ float dens[8];
  const int t = threadIdx.x;
  const int n0 = blockIdx.x * 8;
  const float4* Msrc = (const float4*)&M[(size_t)n0 * 1024];
  float4* Mdst = (float4*)&Ms[0][0][0];
  for (int idx = t; idx < 8 * 256; idx += 256) Mdst[idx] = Msrc[idx];
  if (t < 8) dens[t] = density[n0 + t] + 1.0f;
  __syncthreads();
  const int g = t >> 7, v = t & 127;
  float acc[4][4] = {};
  for (int p0 = 0; p0 < 256; p0 += 4) {
    float4 mv[4][4];
#pragma unroll
    for (int nn = 0; nn < 4; ++nn)
#pragma unroll
      for (int j = 0; j < 4; ++j)
        mv[nn][j] = *(const float4*)&Ms[g * 4 + nn][p0 + j][0];
#pragma unroll
    for (int j = 0; j < 4; ++j) {
      const float w0 = Wl0[(p0 + j) * C + v];
      const float w1 = Wl1[(p0 + j) * C + v];
#pragma unroll
      for (int nn = 0; nn < 4; ++nn) {
        acc[nn][0] = fmaf(mv[nn][j].x, w0, acc[nn][0]);
        acc[nn][1] = fmaf(mv[nn][j].y, w1, acc[nn][1]);
        acc[nn][2] = fmaf(mv[nn][j].z, w1, acc[nn][2]);
        acc[nn][3] = fmaf(mv[nn][j].w, w1, acc[nn][3]);
      }
    }
  }
#pragma unroll
  for (int nn = 0; nn < 4; ++nn) {
    const int n = n0 + g * 4 + nn;
    const float sc = INV_SQRT_2C / dens[g * 4 + nn];
    float4 o;
    o.x = acc[nn][0] * sc; o.y = acc[nn][1] * sc;
    o.z = acc[nn][2] * sc; o.w = acc[nn][3] * sc;
    *(float4*)&out[(size_t)n * 512 + v * 4] = o;
  }
}

// ---------------------------------------------------------------------------
extern "C" void kernel_launch(void* const* d_in, const int* in_sizes, int n_in,
                              void* d_out, int out_size, void* d_ws, size_t ws_size,
                              hipStream_t stream) {
  const float* node_attrs = (const float*)d_in[0];
  const float* node_feats = (const float*)d_in[1];
  const float* edge_attrs = (const float*)d_in[2];
  const float* edge_feats = (const float*)d_in[3];
  const int*   edge_index = (const int*)d_in[4];
  const float* W_up0 = (const float*)d_in[5];
  const float* W_up1 = (const float*)d_in[6];
  const float* R0 = (const float*)d_in[7];
  const float* R1 = (const float*)d_in[8];
  const float* R2 = (const float*)d_in[9];
  const float* R3 = (const float*)d_in[10];
  const float* Wd  = (const float*)d_in[11];
  const float* Wl0 = (const float*)d_in[12];
  const float* Wl1 = (const float*)d_in[13];
  const float* Ws0 = (const float*)d_in[14];
  const float* Ws1 = (const float*)d_in[15];
  float* out = (float*)d_out;

  // Workspace layout (H region kept float-sized = 20MB; split H uses 10.25MB):
  // H0 | H1 | M | density | counts | offsets | cursor | snd_s | rcv_s |
  // ea_s | Bsw0 | Bsw1 | R1a | R2a | R3a (ushort) | ef_s
  unsigned short* H0u = (unsigned short*)d_ws;                 // [N][128] f16
  unsigned short* H1u = H0u + (size_t)N_NODES * 128;           // [N][384] f16
  float* M = (float*)d_ws + (size_t)N_NODES * 512;
  float* density = M + (size_t)N_NODES * 1024;
  int* counts  = (int*)(density + 10000);
  int* offsets = counts + 10016;
  int* cursor  = offsets + 10016;
  int* snd_s   = cursor + 10016;
  int* rcv_s   = snd_s + N_EDGES;
  float* ea_s  = (float*)(rcv_s + N_EDGES);
  unsigned short* Bsw0 = (unsigned short*)(ea_s + (size_t)N_EDGES * 4);
  unsigned short* Bsw1 = Bsw0 + 1280 * 128;
  unsigned short* R1a  = Bsw1 + 1280 * 128;
  unsigned short* R2a  = R1a + 64 * 64;
  unsigned short* R3a  = R2a + 64 * 64;
  float* ef_s  = (float*)(R3a + 64 * 512);

  // zero M + density + counts (contiguous)
  hipMemsetAsync(M, 0, ((size_t)N_NODES * 1024 + 10000 + 10016) * sizeof(float),
                 stream);

  k_node_up<<<N_NODES / 8, 256, 0, stream>>>(node_feats, W_up0, W_up1,
                                             (__half*)H0u, (__half*)H1u);
  k_prep<<<1300, 256, 0, stream>>>(Ws0, Ws1, Bsw0, Bsw1, R1, R1a, R2, R2a, R3,
                                   R3a, edge_index, counts);
  k_scan<<<1, 1024, 0, stream>>>(counts, offsets, cursor);
  k_scatter<<<(N_EDGES + 255) / 256, 256, 0, stream>>>(
      edge_index, edge_attrs, edge_feats, cursor, snd_s, rcv_s, ea_s, ef_s);
  k_mlp_msg<<<N_EDGES / 128, 256, 0, stream>>>(
      ef_s, ea_s, snd_s, rcv_s, offsets, R0, R1a, R2a, R3a, Wd, H0u,
      (const unsigned int*)H1u, M, density);
  k_out<<<N_NODES / 8, 256, 0, stream>>>(M, density, Wl0, Wl1, out);
  k_skip_mfma<<<157 + 469, 256, 0, stream>>>(node_feats, node_attrs, Bsw0, Bsw1,
                                             out + (size_t)N_NODES * 512);
}

// Round 5
// 329.769 us; speedup vs baseline: 1.2468x; 1.2468x over previous
//
#include <hip/hip_runtime.h>
#include <hip/hip_bf16.h>
#include <hip/hip_fp16.h>

// Problem constants
#define N_NODES 10000
#define N_EDGES 128000
constexpr int C = 128;
constexpr int A = 10;

constexpr float INV_SQRT_C  = 0.08838834764831845f;   // 1/sqrt(128)
constexpr float INV_SQRT_R  = 0.35355339059327373f;   // 1/sqrt(8)
constexpr float INV_SQRT_64 = 0.125f;                 // 1/sqrt(64)
constexpr float INV_SQRT_CA = 0.027950849718747374f;  // 1/sqrt(1280)
constexpr float INV_SQRT_2C = 0.0625f;                // 1/sqrt(256)
constexpr float INV_SQRT_3  = 0.57735026918962576f;

typedef short short8 __attribute__((ext_vector_type(8)));
typedef _Float16 f16x8 __attribute__((ext_vector_type(8)));
typedef _Float16 f16x2 __attribute__((ext_vector_type(2)));
typedef float f32x4 __attribute__((ext_vector_type(4)));

__device__ __forceinline__ float silu_f(float x) { return x / (1.0f + __expf(-x)); }

__device__ __forceinline__ void atomic_add_f32(float* p, float v) {
  __hip_atomic_fetch_add(p, v, __ATOMIC_RELAXED, __HIP_MEMORY_SCOPE_AGENT);
}

__device__ __forceinline__ unsigned short f2h(float f) {
  return __builtin_bit_cast(unsigned short, (_Float16)f);  // RNE
}

__device__ __forceinline__ unsigned int pk2h(float a, float b) {
  auto h = __builtin_amdgcn_cvt_pkrtz(a, b);  // __fp16 ext_vector(2)
  return __builtin_bit_cast(unsigned int, h);
}

__device__ __forceinline__ unsigned int pkmul_h2(unsigned int x, unsigned int y) {
  const f16x2 a = __builtin_bit_cast(f16x2, x), b = __builtin_bit_cast(f16x2, y);
  return __builtin_bit_cast(unsigned int, a * b);  // v_pk_mul_f16
}

__device__ __forceinline__ float4 h4tof4(uint2 v) {
  const __half2 lo = __builtin_bit_cast(__half2, v.x);
  const __half2 hi = __builtin_bit_cast(__half2, v.y);
  const float2 flo = __half22float2(lo), fhi = __half22float2(hi);
  return make_float4(flo.x, flo.y, fhi.x, fhi.y);
}

// ---------------------------------------------------------------------------
// K1: Hh[n, u*4+0] = h0[n,u],  Hh[n, u*4+1+k] = h1[n,u,k]  (fp16, unified:
// one aligned uint2 store per (n,v) -- the coalesced shape; R4's split-H
// scalar stores regressed).
// ---------------------------------------------------------------------------
__global__ __launch_bounds__(256) void k_node_up(
    const float* __restrict__ nf, const float* __restrict__ Wu0,
    const float* __restrict__ Wu1, __half* __restrict__ Hh) {
  __shared__ __align__(16) float xs[8][C][4];
  const int t = threadIdx.x;
  const int n0 = blockIdx.x * 8;
  for (int idx = t; idx < 8 * 512; idx += 256) {
    const int nn = idx >> 9, q = idx & 511;
    const float val = nf[(size_t)(n0 + nn) * 512 + q];
    if (q < C) xs[nn][q][0] = val;
    else { const int r = q - C; xs[nn][r / 3][1 + r % 3] = val; }
  }
  __syncthreads();
  const int g = t >> 7, v = t & 127;
  float acc[4][4] = {};
  for (int u = 0; u < C; ++u) {
    const float w0 = Wu0[u * C + v];
    const float w1 = Wu1[u * C + v];
#pragma unroll
    for (int nn = 0; nn < 4; ++nn) {
      const float4 xv = *(const float4*)&xs[g * 4 + nn][u][0];
      acc[nn][0] = fmaf(xv.x, w0, acc[nn][0]);
      acc[nn][1] = fmaf(xv.y, w1, acc[nn][1]);
      acc[nn][2] = fmaf(xv.z, w1, acc[nn][2]);
      acc[nn][3] = fmaf(xv.w, w1, acc[nn][3]);
    }
  }
#pragma unroll
  for (int nn = 0; nn < 4; ++nn) {
    const int n = n0 + g * 4 + nn;
    uint2 o;
    o.x = pk2h(acc[nn][0] * INV_SQRT_C, acc[nn][1] * INV_SQRT_C);
    o.y = pk2h(acc[nn][2] * INV_SQRT_C, acc[nn][3] * INV_SQRT_C);
    *(uint2*)&Hh[(size_t)n * 512 + v * 4] = o;
  }
}

// ---------------------------------------------------------------------------
// cvtw helper: weight (K x N fp32, row-major) -> f16 A-operand swizzle of W^T.
// ---------------------------------------------------------------------------
__device__ __forceinline__ void cvtw(const float* __restrict__ src,
                                     unsigned short* __restrict__ dst,
                                     int idx, int lgN, int KT) {
  const int k = idx >> lgN;
  const int n = idx & ((1 << lgN) - 1);
  dst[((n * KT + (k >> 5)) << 5) + (k & 31)] = f2h(src[idx]);
}

// ---------------------------------------------------------------------------
// k_prep (merged): skip-weight cvt (f16, k'=a*128+u permuted) + 3x cvt_w +
// edge histogram. All-independent elementwise work, one launch.
// ---------------------------------------------------------------------------
__global__ __launch_bounds__(256) void k_prep(
    const float* __restrict__ W0, const float* __restrict__ W1,
    unsigned short* __restrict__ B0, unsigned short* __restrict__ B1,
    const float* __restrict__ R1, unsigned short* __restrict__ R1a,
    const float* __restrict__ R2, unsigned short* __restrict__ R2a,
    const float* __restrict__ R3, unsigned short* __restrict__ R3a,
    const int* __restrict__ eidx, int* __restrict__ counts) {
  const int b = blockIdx.x, t = threadIdx.x;
  if (b < 640) {
    // skip GEMM B operand: k = u*10+a -> permuted k' = a*128+u (so the
    // A-repack in k_skip_mfma has constant a / contiguous u per 8-chunk).
    const int idx = b * 256 + t;
    const int k = idx >> 7, col = idx & 127;
    const int u = k / 10, a = k - u * 10;
    const int kp = a * 128 + u;
    const int dst = ((kp >> 5) * 128 + col) * 32 + (kp & 31);
    B0[dst] = f2h(W0[idx]);
    B1[dst] = f2h(W1[idx]);
  } else if (b < 656) {
    cvtw(R1, R1a, (b - 640) * 256 + t, 6, 2);
  } else if (b < 672) {
    cvtw(R2, R2a, (b - 656) * 256 + t, 6, 2);
  } else if (b < 800) {
    cvtw(R3, R3a, (b - 672) * 256 + t, 9, 2);
  } else {
    const int e = (b - 800) * 256 + t;
    if (e < N_EDGES) atomicAdd(&counts[eidx[N_EDGES + e]], 1);
  }
}

// ---------------------------------------------------------------------------
// K2 (MFMA): sc as two f16 GEMMs with k' = a*128+u contraction order.
// attr row register-cached; repack per K-step = 1 ds_read_b128 +
// 4 v_pk_mul_f16 + 1 ds_write_b128. xs padded [64][136].
// ---------------------------------------------------------------------------
__global__ __launch_bounds__(256) void k_skip_mfma(
    const float* __restrict__ nf, const float* __restrict__ attrs,
    const unsigned short* __restrict__ B0, const unsigned short* __restrict__ B1,
    float* __restrict__ out_sc) {
  __shared__ __align__(16) unsigned short xs[64][136];     // 17 KB f16 (+pad)
  __shared__ float at[64][10];                             // 2.5 KB
  __shared__ __align__(16) unsigned short zs[2][64][40];   // 10 KB

  const int t = threadIdx.x;
  const int wave = t >> 6, lane = t & 63;
  const bool isG0 = blockIdx.x < 157;
  const int r0 = isG0 ? blockIdx.x * 64 : (blockIdx.x - 157) * 64;
  const int rcount = isG0 ? 10000 : 30000;
  const unsigned short* __restrict__ Bsw = isG0 ? B0 : B1;

  for (int idx = t; idx < 64 * 128; idx += 256) {
    const int i = idx >> 7, u = idx & 127;
    const int r = r0 + i;
    float v = 0.f;
    if (r < rcount) {
      if (isG0) v = nf[(size_t)r * 512 + u];
      else {
        const int n = r / 3, kc = r - n * 3;
        v = nf[(size_t)n * 512 + 128 + u * 3 + kc];
      }
    }
    xs[i][u] = f2h(v);
  }
  for (int idx = t; idx < 640; idx += 256) {
    const int i = idx / 10, a = idx - (idx / 10) * 10;
    const int r = r0 + i;
    float v = 0.f;
    if (r < rcount) v = attrs[(size_t)(isG0 ? r : r / 3) * 10 + a];
    at[i][a] = v;
  }
  __syncthreads();

  const int m = lane & 15, q = lane >> 4;
  const int colB = wave * 32;
  const int rr = t >> 2;
  const int off = (t & 3) * 8;

  // attr row -> 10 half2-broadcast registers (compile-time indexed below)
  unsigned int atr2[10];
#pragma unroll
  for (int a = 0; a < 10; ++a) {
    const unsigned int h = f2h(at[rr][a]);
    atr2[a] = h | (h << 16);
  }

  f32x4 acc[4][2];
#pragma unroll
  for (int rt = 0; rt < 4; ++rt)
#pragma unroll
    for (int ct = 0; ct < 2; ++ct) acc[rt][ct] = (f32x4){0.f, 0.f, 0.f, 0.f};

#pragma unroll
  for (int a = 0; a < 10; ++a) {
    const unsigned int av2 = atr2[a];
#pragma unroll
    for (int kk = 0; kk < 4; ++kk) {
      const int kt = a * 4 + kk;
      const int buf = kt & 1;
      {
        // k' = a*128 + (kk*32 + off + j): constant a, contiguous u
        const uint4 xv = *(const uint4*)&xs[rr][kk * 32 + off];
        uint4 z;
        z.x = pkmul_h2(xv.x, av2);
        z.y = pkmul_h2(xv.y, av2);
        z.z = pkmul_h2(xv.z, av2);
        z.w = pkmul_h2(xv.w, av2);
        *(uint4*)&zs[buf][rr][off] = z;
      }
      __syncthreads();

      f16x8 bfrag[2];
#pragma unroll
      for (int ct = 0; ct < 2; ++ct) {
        const unsigned short* bp =
            &Bsw[(size_t)(kt * 128 + colB + ct * 16 + m) * 32 + q * 8];
        bfrag[ct] = *(const f16x8*)bp;
      }
#pragma unroll
      for (int rt = 0; rt < 4; ++rt) {
        const f16x8 afrag = *(const f16x8*)&zs[buf][rt * 16 + m][q * 8];
#pragma unroll
        for (int ct = 0; ct < 2; ++ct)
          acc[rt][ct] = __builtin_amdgcn_mfma_f32_16x16x32_f16(
              afrag, bfrag[ct], acc[rt][ct], 0, 0, 0);
      }
      // no trailing barrier: next iteration writes the other zs buffer
    }
  }

#pragma unroll
  for (int rt = 0; rt < 4; ++rt) {
#pragma unroll
    for (int reg = 0; reg < 4; ++reg) {
      const int rloc = rt * 16 + q * 4 + reg;
      const int r = r0 + rloc;
      if (r < rcount) {
#pragma unroll
        for (int ct = 0; ct < 2; ++ct) {
          const int v = colB + ct * 16 + m;
          const float val = acc[rt][ct][reg] * INV_SQRT_CA;
          if (isG0) {
            out_sc[(size_t)r * 512 + v] = val;
          } else {
            const int n = r / 3, kc = r - (r / 3) * 3;
            out_sc[(size_t)n * 512 + 128 + v * 3 + kc] = val;
          }
        }
      }
    }
  }
}

// ---------------------------------------------------------------------------
// Sort-by-receiver: scan -> scatter (histogram lives in k_prep)
// ---------------------------------------------------------------------------
__global__ __launch_bounds__(1024) void k_scan(const int* __restrict__ counts,
                                               int* __restrict__ offsets,
                                               int* __restrict__ cursor) {
  __shared__ int part[1024];
  const int t = threadIdx.x;
  int local[10];
  int s = 0;
#pragma unroll
  for (int i = 0; i < 10; ++i) {
    const int idx = t * 10 + i;
    const int c = (idx < N_NODES) ? counts[idx] : 0;
    local[i] = s;
    s += c;
  }
  part[t] = s;
  __syncthreads();
  for (int off = 1; off < 1024; off <<= 1) {
    const int add = (t >= off) ? part[t - off] : 0;
    __syncthreads();
    part[t] += add;
    __syncthreads();
  }
  const int pre = (t > 0) ? part[t - 1] : 0;
#pragma unroll
  for (int i = 0; i < 10; ++i) {
    const int idx = t * 10 + i;
    if (idx < N_NODES) {
      const int o = pre + local[i];
      offsets[idx] = o;
      cursor[idx] = o;
    }
  }
  if (t == 1023) offsets[N_NODES] = part[1023];
}

__global__ __launch_bounds__(256) void k_scatter(
    const int* __restrict__ eidx, const float* __restrict__ ea_g,
    const float* __restrict__ ef_g,
    int* __restrict__ cursor,
    int* __restrict__ snd_s, int* __restrict__ rcv_s,
    float* __restrict__ ea_s, float* __restrict__ ef_s) {
  const int e = blockIdx.x * 256 + threadIdx.x;
  if (e < N_EDGES) {
    const int r = eidx[N_EDGES + e];
    const int pos = atomicAdd(&cursor[r], 1);
    snd_s[pos] = eidx[e];
    rcv_s[pos] = r;
    ((float4*)ea_s)[pos] = ((const float4*)ea_g)[e];
    ((float4*)ef_s)[pos * 2]     = ((const float4*)ef_g)[e * 2];
    ((float4*)ef_s)[pos * 2 + 1] = ((const float4*)ef_g)[e * 2 + 1];
  }
}

// ---------------------------------------------------------------------------
// K3 (fused): edge MLP (MFMA) + message formation + segmented reduction.
// Pair-tile L4: wave w computes channel tiles {base..base+3} U {base+8..+11};
// each lane holds channel pairs -> message loop reads ONE ds_read_b32/edge.
//
// v5 (revert-to-best): R2's proven structure (depth-8 hA/hB prefetch,
// UNIFIED Hh uint2 gather -- the aligned 8B shape; R4's split-H sub-dword
// gathers regressed). Kept from R4: rc/sn batched as int4 (LDS-only) with
// sn padded to 144 for a branch-free tail refill.
// ---------------------------------------------------------------------------
__global__ __launch_bounds__(256, 4) void k_mlp_msg(
    const float* __restrict__ ef_s, const float* __restrict__ ea_s,
    const int* __restrict__ snd_s, const int* __restrict__ rcv_s,
    const int* __restrict__ offsets,
    const float* __restrict__ R0, const unsigned short* __restrict__ R1a,
    const unsigned short* __restrict__ R2a, const unsigned short* __restrict__ R3a,
    const float* __restrict__ Wd, const __half* __restrict__ Hh,
    float* __restrict__ M, float* __restrict__ density) {
  __shared__ __align__(16) unsigned short actA[128][72];  // 18 KB (live whole kernel)
  __shared__ __align__(16) unsigned char uni[18432];      // 18 KB union: efs|actB|wls2
  __shared__ __align__(16) float ys[128][4];              // 2 KB
  __shared__ __align__(16) int sn[144];                   // 576 B (refill-padded)
  __shared__ __align__(16) int rc[128];                   // 512 B
  // lifetimes: efs: stage..L1 | actB: L2..L3 | wls2: L4 chunks (all barrier-separated)
  float (*efs)[9] = (float (*)[9]) & uni[0];                       // [128][9]
  unsigned short (*actB)[72] = (unsigned short (*)[72]) & uni[0];  // [128][72]
  __half (*wls2)[536] = (__half (*)[536]) & uni[0];                // [16][536]

  const int t = threadIdx.x;
  const int wave = t >> 6, lane = t & 63, m = lane & 15, q = lane >> 4;
  const int e0 = blockIdx.x * 128;

  // stage sorted edge feats: 256 threads x float4
  {
    const float4 v = *(const float4*)&ef_s[(size_t)e0 * 8 + t * 4];
    const int e = t >> 1, c0 = (t & 1) * 4;
    efs[e][c0] = v.x; efs[e][c0 + 1] = v.y;
    efs[e][c0 + 2] = v.z; efs[e][c0 + 3] = v.w;
  }
  if (t < 128) {
    *(float4*)&ys[t][0] = ((const float4*)ea_s)[e0 + t];
    sn[t] = snd_s[e0 + t];
    rc[t] = rcv_s[e0 + t];
  } else if (t < 144) {
    sn[t] = 0;  // pad: tail refill reads sn[128..143]; node 0 is always valid
  }
  __syncthreads();

  const int u = t & 127, half = t >> 7;
  const size_t ucol = (size_t)(u << 2);
  // depth-8 H prefetch: two 4-edge groups (issued early; consumed in msg loop)
  uint2 hA[4], hB[4];
#pragma unroll
  for (int j = 0; j < 4; ++j)
    hA[j] = *(const uint2*)&Hh[(size_t)sn[j] * 512 + ucol];
#pragma unroll
  for (int j = 0; j < 4; ++j)
    hB[j] = *(const uint2*)&Hh[(size_t)sn[4 + j] * 512 + ucol];

  // density (one thread per edge)
  if (t < 128) {
    float s = 0.f;
#pragma unroll
    for (int i = 0; i < 8; ++i) s = fmaf(efs[t][i], Wd[i], s);
    s *= INV_SQRT_R;
    atomic_add_f32(&density[rc[t]], tanhf(s * s));
  }

  // L1: 8 -> 64 (VALU), silu, f16 into actA.
  {
    const int e = t & 127, j0 = (t >> 7) * 32;
    float a[32] = {};
#pragma unroll
    for (int i = 0; i < 8; ++i) {
      const float v = efs[e][i];
#pragma unroll
      for (int jj = 0; jj < 32; ++jj)
        a[jj] = fmaf(v, R0[i * 64 + j0 + jj], a[jj]);
    }
#pragma unroll
    for (int g = 0; g < 8; ++g) {
      uint2 pk;
      pk.x = pk2h(silu_f(a[4 * g] * INV_SQRT_R), silu_f(a[4 * g + 1] * INV_SQRT_R));
      pk.y = pk2h(silu_f(a[4 * g + 2] * INV_SQRT_R), silu_f(a[4 * g + 3] * INV_SQRT_R));
      *(uint2*)&actA[e][j0 + g * 4] = pk;
    }
  }
  __syncthreads();

  // L2: C = R1^T . actA -> silu -> actB.  (efs dead from here; actB aliases uni)
  {
    const f16x8 af0 = *(const f16x8*)&R1a[(((wave * 16 + m) * 2 + 0) << 5) + q * 8];
    const f16x8 af1 = *(const f16x8*)&R1a[(((wave * 16 + m) * 2 + 1) << 5) + q * 8];
#pragma unroll
    for (int et = 0; et < 8; ++et) {
      const f16x8 bf0 = *(const f16x8*)&actA[et * 16 + m][q * 8];
      const f16x8 bf1 = *(const f16x8*)&actA[et * 16 + m][32 + q * 8];
      f32x4 c = {0.f, 0.f, 0.f, 0.f};
      c = __builtin_amdgcn_mfma_f32_16x16x32_f16(af0, bf0, c, 0, 0, 0);
      c = __builtin_amdgcn_mfma_f32_16x16x32_f16(af1, bf1, c, 0, 0, 0);
      uint2 pk;
      pk.x = pk2h(silu_f(c[0] * INV_SQRT_64), silu_f(c[1] * INV_SQRT_64));
      pk.y = pk2h(silu_f(c[2] * INV_SQRT_64), silu_f(c[3] * INV_SQRT_64));
      *(uint2*)&actB[et * 16 + m][wave * 16 + q * 4] = pk;
    }
  }
  __syncthreads();

  // L3: C = R2^T . actB -> silu -> actA
  {
    const f16x8 af0 = *(const f16x8*)&R2a[(((wave * 16 + m) * 2 + 0) << 5) + q * 8];
    const f16x8 af1 = *(const f16x8*)&R2a[(((wave * 16 + m) * 2 + 1) << 5) + q * 8];
#pragma unroll
    for (int et = 0; et < 8; ++et) {
      const f16x8 bf0 = *(const f16x8*)&actB[et * 16 + m][q * 8];
      const f16x8 bf1 = *(const f16x8*)&actB[et * 16 + m][32 + q * 8];
      f32x4 c = {0.f, 0.f, 0.f, 0.f};
      c = __builtin_amdgcn_mfma_f32_16x16x32_f16(af0, bf0, c, 0, 0, 0);
      c = __builtin_amdgcn_mfma_f32_16x16x32_f16(af1, bf1, c, 0, 0, 0);
      uint2 pk;
      pk.x = pk2h(silu_f(c[0] * INV_SQRT_64), silu_f(c[1] * INV_SQRT_64));
      pk.y = pk2h(silu_f(c[2] * INV_SQRT_64), silu_f(c[3] * INV_SQRT_64));
      *(uint2*)&actA[et * 16 + m][wave * 16 + q * 4] = pk;
    }
  }
  __syncthreads();  // actA now final; read-only below (cross-wave) -> keep

  // L4 weights, pair-tile assignment: lower tile JL, partner JH = JL + 8.
  const int baseJ = (wave & 1) * 4 + (wave >> 1) * 16;
  f16x8 afL[4][2], afH[4][2];
#pragma unroll
  for (int i = 0; i < 4; ++i) {
#pragma unroll
    for (int kt = 0; kt < 2; ++kt) {
      const int JL = baseJ + i, JH = JL + 8;
      afL[i][kt] = *(const f16x8*)&R3a[(((JL * 16 + m) * 2 + kt) << 5) + q * 8];
      afH[i][kt] = *(const f16x8*)&R3a[(((JH * 16 + m) * 2 + kt) << 5) + q * 8];
    }
  }

  // message accumulation state
  float a0 = 0.f, a1 = 0.f, a2 = 0.f, a3 = 0.f;
  int cur = rc[0];
  int s0c = offsets[cur], s1c = offsets[cur + 1];  // segment-bound prefetch
  const int colx = (half ? 128 + u : u) * 2;

  auto flush = [&](int n, int s0, int s1) {
    float* Mp = &M[(size_t)n * 1024 + (half << 9) + (u << 2)];
    if (s0 >= e0 && s1 <= e0 + 128) {
      *(float4*)Mp = make_float4(a0, a1, a2, a3);
    } else {
      atomic_add_f32(Mp + 0, a0);
      atomic_add_f32(Mp + 1, a1);
      atomic_add_f32(Mp + 2, a2);
      atomic_add_f32(Mp + 3, a3);
    }
  };

  auto proc = [&](const uint2 hcur, unsigned int pr, const float4 yv, int n) {
    if (n != cur) {  // wave-uniform
      flush(cur, s0c, s1c);
      a0 = a1 = a2 = a3 = 0.f;
      cur = n;
      s0c = offsets[n];       // issued at segment start,
      s1c = offsets[n + 1];   // consumed at segment end -> latency hidden
    }
    const float4 h4 = h4tof4(hcur);
    const __half2 ph = __builtin_bit_cast(__half2, pr);
    const float2 pw = __half22float2(ph);
    if (half == 0) {
      a0 = fmaf(pw.x * h4.x, yv.x, a0);
      const float c1 = pw.y * h4.x;
      a1 = fmaf(c1, yv.y, a1);
      a2 = fmaf(c1, yv.z, a2);
      a3 = fmaf(c1, yv.w, a3);
    } else {
      const float dt = h4.y * yv.y + h4.z * yv.z + h4.w * yv.w;
      a0 = fmaf(pw.y * dt, INV_SQRT_3, a0);
      const float c3 = pw.x * yv.x;
      a1 = fmaf(c3, h4.y, a1);
      a2 = fmaf(c3, h4.z, a2);
      a3 = fmaf(c3, h4.w, a3);
    }
  };

  // Per 4-edge group: batch-issue the LDS reads (wls2 b32 x4, ys b128 x4,
  // rc int4, sn int4), process, refill this group's H buffer +8 ahead.
#define MSG_GROUP(G, HX)                                                    \
  {                                                                         \
    const int gb = ch * 16 + (G) * 4;                                       \
    unsigned int prv[4];                                                    \
    float4 yv4[4];                                                          \
    _Pragma("unroll") for (int j = 0; j < 4; ++j)                           \
        prv[j] = *(const unsigned int*)&wls2[(G) * 4 + j][colx];            \
    _Pragma("unroll") for (int j = 0; j < 4; ++j)                           \
        yv4[j] = *(const float4*)&ys[gb + j][0];                            \
    const int4 rc4 = *(const int4*)&rc[gb];                                 \
    proc(HX[0], prv[0], yv4[0], rc4.x);                                     \
    proc(HX[1], prv[1], yv4[1], rc4.y);                                     \
    proc(HX[2], prv[2], yv4[2], rc4.z);                                     \
    proc(HX[3], prv[3], yv4[3], rc4.w);                                     \
    const int4 sn4 = *(const int4*)&sn[gb + 8];                             \
    HX[0] = *(const uint2*)&Hh[(size_t)sn4.x * 512 + ucol];                 \
    HX[1] = *(const uint2*)&Hh[(size_t)sn4.y * 512 + ucol];                 \
    HX[2] = *(const uint2*)&Hh[(size_t)sn4.z * 512 + ucol];                 \
    HX[3] = *(const uint2*)&Hh[(size_t)sn4.w * 512 + ucol];                 \
  }

  // 8 chunks of 16 edges: L4 MFMA into wls2 (union region), then messages.
  // BARRIER-FREE: wave w writes wls2 pair-cols [w*64,(w+1)*64) and reads the
  // same range -> no cross-wave hazard; within-wave write->read ordering
  // enforced by compiler-inserted lgkmcnt.
#pragma unroll 1
  for (int ch = 0; ch < 8; ++ch) {
    {
      const f16x8 bf0 = *(const f16x8*)&actA[ch * 16 + m][q * 8];
      const f16x8 bf1 = *(const f16x8*)&actA[ch * 16 + m][32 + q * 8];
#pragma unroll
      for (int i = 0; i < 4; ++i) {
        f32x4 cL = {0.f, 0.f, 0.f, 0.f}, cH = {0.f, 0.f, 0.f, 0.f};
        cL = __builtin_amdgcn_mfma_f32_16x16x32_f16(afL[i][0], bf0, cL, 0, 0, 0);
        cL = __builtin_amdgcn_mfma_f32_16x16x32_f16(afL[i][1], bf1, cL, 0, 0, 0);
        cH = __builtin_amdgcn_mfma_f32_16x16x32_f16(afH[i][0], bf0, cH, 0, 0, 0);
        cH = __builtin_amdgcn_mfma_f32_16x16x32_f16(afH[i][1], bf1, cH, 0, 0, 0);
        uint4 pk;
        pk.x = pk2h(cL[0] * INV_SQRT_64, cH[0] * INV_SQRT_64);
        pk.y = pk2h(cL[1] * INV_SQRT_64, cH[1] * INV_SQRT_64);
        pk.z = pk2h(cL[2] * INV_SQRT_64, cH[2] * INV_SQRT_64);
        pk.w = pk2h(cL[3] * INV_SQRT_64, cH[3] * INV_SQRT_64);
        const int JL = baseJ + i;
        const int pidx0 = ((JL < 8) ? JL * 16 : (JL - 16) * 16 + 128) + q * 4;
        *(uint4*)&wls2[m][pidx0 * 2] = pk;
      }
    }
    MSG_GROUP(0, hA)
    MSG_GROUP(1, hB)
    MSG_GROUP(2, hA)
    MSG_GROUP(3, hB)
  }
#undef MSG_GROUP
  flush(cur, s0c, s1c);
}

// ---------------------------------------------------------------------------
// K5: out0 = M0 @ Wl0 /16/denom; out1[.,.,k] = M1[...,k] @ Wl1 /16/denom
// ---------------------------------------------------------------------------
__global__ __launch_bounds__(256) void k_out(
    const float* __restrict__ M, const float* __restrict__ density,
    const float* __restrict__ Wl0, const float* __restrict__ Wl1,
    float* __restrict__ out) {
  __shared__ __align__(16) float Ms[8][256][4];  // 32 KB
  __shared__ float dens[8];
  const int t = threadIdx.x;
  const int n0 = blockIdx.x * 8;
  const float4* Msrc = (const float4*)&M[(size_t)n0 * 1024];
  float4* Mdst = (float4*)&Ms[0][0][0];
  for (int idx = t; idx < 8 * 256; idx += 256) Mdst[idx] = Msrc[idx];
  if (t < 8) dens[t] = density[n0 + t] + 1.0f;
  __syncthreads();
  const int g = t >> 7, v = t & 127;
  float acc[4][4] = {};
  for (int p0 = 0; p0 < 256; p0 += 4) {
    float4 mv[4][4];
#pragma unroll
    for (int nn = 0; nn < 4; ++nn)
#pragma unroll
      for (int j = 0; j < 4; ++j)
        mv[nn][j] = *(const float4*)&Ms[g * 4 + nn][p0 + j][0];
#pragma unroll
    for (int j = 0; j < 4; ++j) {
      const float w0 = Wl0[(p0 + j) * C + v];
      const float w1 = Wl1[(p0 + j) * C + v];
#pragma unroll
      for (int nn = 0; nn < 4; ++nn) {
        acc[nn][0] = fmaf(mv[nn][j].x, w0, acc[nn][0]);
        acc[nn][1] = fmaf(mv[nn][j].y, w1, acc[nn][1]);
        acc[nn][2] = fmaf(mv[nn][j].z, w1, acc[nn][2]);
        acc[nn][3] = fmaf(mv[nn][j].w, w1, acc[nn][3]);
      }
    }
  }
#pragma unroll
  for (int nn = 0; nn < 4; ++nn) {
    const int n = n0 + g * 4 + nn;
    const float sc = INV_SQRT_2C / dens[g * 4 + nn];
    float4 o;
    o.x = acc[nn][0] * sc; o.y = acc[nn][1] * sc;
    o.z = acc[nn][2] * sc; o.w = acc[nn][3] * sc;
    *(float4*)&out[(size_t)n * 512 + v * 4] = o;
  }
}

// ---------------------------------------------------------------------------
extern "C" void kernel_launch(void* const* d_in, const int* in_sizes, int n_in,
                              void* d_out, int out_size, void* d_ws, size_t ws_size,
                              hipStream_t stream) {
  const float* node_attrs = (const float*)d_in[0];
  const float* node_feats = (const float*)d_in[1];
  const float* edge_attrs = (const float*)d_in[2];
  const float* edge_feats = (const float*)d_in[3];
  const int*   edge_index = (const int*)d_in[4];
  const float* W_up0 = (const float*)d_in[5];
  const float* W_up1 = (const float*)d_in[6];
  const float* R0 = (const float*)d_in[7];
  const float* R1 = (const float*)d_in[8];
  const float* R2 = (const float*)d_in[9];
  const float* R3 = (const float*)d_in[10];
  const float* Wd  = (const float*)d_in[11];
  const float* Wl0 = (const float*)d_in[12];
  const float* Wl1 = (const float*)d_in[13];
  const float* Ws0 = (const float*)d_in[14];
  const float* Ws1 = (const float*)d_in[15];
  float* out = (float*)d_out;

  // Workspace layout (H region kept float-sized, used as half):
  // H | M | density | counts | offsets | cursor | snd_s | rcv_s |
  // ea_s | Bsw0 | Bsw1 | R1a | R2a | R3a (ushort) | ef_s
  __half* Hh = (__half*)d_ws;
  float* M = (float*)d_ws + (size_t)N_NODES * 512;
  float* density = M + (size_t)N_NODES * 1024;
  int* counts  = (int*)(density + 10000);
  int* offsets = counts + 10016;
  int* cursor  = offsets + 10016;
  int* snd_s   = cursor + 10016;
  int* rcv_s   = snd_s + N_EDGES;
  float* ea_s  = (float*)(rcv_s + N_EDGES);
  unsigned short* Bsw0 = (unsigned short*)(ea_s + (size_t)N_EDGES * 4);
  unsigned short* Bsw1 = Bsw0 + 1280 * 128;
  unsigned short* R1a  = Bsw1 + 1280 * 128;
  unsigned short* R2a  = R1a + 64 * 64;
  unsigned short* R3a  = R2a + 64 * 64;
  float* ef_s  = (float*)(R3a + 64 * 512);

  // zero M + density + counts (contiguous)
  hipMemsetAsync(M, 0, ((size_t)N_NODES * 1024 + 10000 + 10016) * sizeof(float),
                 stream);

  k_node_up<<<N_NODES / 8, 256, 0, stream>>>(node_feats, W_up0, W_up1, Hh);
  k_prep<<<1300, 256, 0, stream>>>(Ws0, Ws1, Bsw0, Bsw1, R1, R1a, R2, R2a, R3,
                                   R3a, edge_index, counts);
  k_scan<<<1, 1024, 0, stream>>>(counts, offsets, cursor);
  k_scatter<<<(N_EDGES + 255) / 256, 256, 0, stream>>>(
      edge_index, edge_attrs, edge_feats, cursor, snd_s, rcv_s, ea_s, ef_s);
  k_mlp_msg<<<N_EDGES / 128, 256, 0, stream>>>(ef_s, ea_s, snd_s, rcv_s,
                                               offsets, R0, R1a, R2a, R3a, Wd,
                                               Hh, M, density);
  k_out<<<N_NODES / 8, 256, 0, stream>>>(M, density, Wl0, Wl1, out);
  k_skip_mfma<<<157 + 469, 256, 0, stream>>>(node_feats, node_attrs, Bsw0, Bsw1,
                                             out + (size_t)N_NODES * 512);
}